// Round 5
// baseline (1666.010 us; speedup 1.0000x reference)
//
#include <hip/hip_runtime.h>
#include <math.h>

#define BB 4
#define LL 2048
#define DD 512
#define NH 8
#define DINNER 2048
#define NLAYERS 4
#define MM (BB * LL)  // 8192

typedef __attribute__((ext_vector_type(8))) __bf16 bf16x8;
typedef __attribute__((ext_vector_type(4))) float f32x4;
typedef __attribute__((ext_vector_type(4))) unsigned short us4;

__device__ __forceinline__ unsigned short f2b(float f) {
  union { float f; unsigned u; } v; v.f = f;
  unsigned r = v.u + 0x7fffu + ((v.u >> 16) & 1u);
  return (unsigned short)(r >> 16);
}
__device__ __forceinline__ float b2f(unsigned short h) {
  union { unsigned u; float f; } v; v.u = ((unsigned)h) << 16; return v.f;
}

__device__ __forceinline__ void gload16(const void* g, void* l) {
  __builtin_amdgcn_global_load_lds(
      (const __attribute__((address_space(1))) void*)g,
      (__attribute__((address_space(3))) void*)l, 16, 0, 0);
}

// ---------------- init: temporal enc + embedding gather ----------------
__global__ __launch_bounds__(512) void init_kernel(
    const int* __restrict__ etype, const float* __restrict__ etime,
    const float* __restrict__ npm, const float* __restrict__ emb,
    float* __restrict__ tem, float* __restrict__ x) {
  int row = blockIdx.x;
  int d = threadIdx.x;
  float t = etime[row];
  float mask = npm[row];
  int dd = d & ~1;
  float pv = expf(9.210340371976184f * ((float)dd * (1.0f / (float)DD)));
  float r = t / pv;
  float val = (d & 1) ? cosf(r) : sinf(r);
  tem[(size_t)row * DD + d] = val * mask;
  int ty = etype[row];
  x[(size_t)row * DD + d] = emb[(size_t)ty * DD + d];
}

// ---------------- x + tem -> fp32 + bf16 ----------------
__global__ __launch_bounds__(256) void add_tem_kernel(
    const float4* __restrict__ x, const float4* __restrict__ tem,
    float4* __restrict__ xa, us4* __restrict__ xab) {
  int i = blockIdx.x * 256 + threadIdx.x;
  float4 a = x[i], t = tem[i];
  float4 s = make_float4(a.x + t.x, a.y + t.y, a.z + t.z, a.w + t.w);
  xa[i] = s;
  us4 p = {f2b(s.x), f2b(s.y), f2b(s.z), f2b(s.w)};
  xab[i] = p;
}

// ---------------- weight transpose+convert: fp32 [K][N] -> bf16 [N][K] ----
__global__ __launch_bounds__(256) void wtrans_kernel(
    const float* __restrict__ in, unsigned short* __restrict__ out,
    int K, int N, long in_ls, long out_ls) {
  __shared__ float t[32][33];
  int l = blockIdx.z;
  int n0 = blockIdx.x * 32, k0 = blockIdx.y * 32;
  int tx = threadIdx.x & 31, ty = threadIdx.x >> 5;
  const float* ip = in + (size_t)l * in_ls;
  unsigned short* op = out + (size_t)l * out_ls;
#pragma unroll
  for (int r = ty; r < 32; r += 8)
    t[r][tx] = ip[(size_t)(k0 + r) * N + n0 + tx];
  __syncthreads();
#pragma unroll
  for (int r = ty; r < 32; r += 8)
    op[(size_t)(n0 + r) * K + k0 + tx] = f2b(t[tx][r]);
}

// ---- MFMA GEMM: C[M,N] = A(bf16 [M,K]) @ WT(bf16 [N,K])^T, tile BM x 128 --
template <int BM, bool BIAS, bool RES, bool GELU_, bool OBF16>
__global__ __launch_bounds__(256) void gemm_kernel(
    const unsigned short* __restrict__ A, const unsigned short* __restrict__ WT,
    const float* __restrict__ bias, const float* __restrict__ res, int ldres,
    void* __restrict__ Cv, int ldc, int M, int N, int K) {
  __shared__ unsigned short As[BM * 32];
  __shared__ unsigned short Bs[128 * 32];
  constexpr int NT = (BM == 128) ? 4 : 2;  // per-wave 16-col tiles
  int tid = threadIdx.x;
  int w = tid >> 6, l = tid & 63;
  int li = l & 15, g = l >> 4;
  int row0 = blockIdx.y * BM, col0 = blockIdx.x * 128;
  int wm = (BM == 128) ? (w & 1) * 64 : 0;         // row base within tile
  int wnb = (BM == 128) ? (w >> 1) * 64 : w * 32;  // col base within tile
  f32x4 acc[4][NT];
#pragma unroll
  for (int i = 0; i < 4; i++)
#pragma unroll
    for (int j = 0; j < NT; j++) acc[i][j] = (f32x4){0.f, 0.f, 0.f, 0.f};

  int lr = l >> 2;
  int lc = (l & 3) ^ (lr & 3);

  for (int k0 = 0; k0 < K; k0 += 32) {
    if (BM == 128) {
#pragma unroll
      for (int i = 0; i < 2; i++) {
        int ai = w * 2 + i;
        gload16(A + (size_t)(row0 + ai * 16 + lr) * K + k0 + lc * 8,
                &As[ai * 512]);
        gload16(WT + (size_t)(col0 + ai * 16 + lr) * K + k0 + lc * 8,
                &Bs[ai * 512]);
      }
    } else {
      gload16(A + (size_t)(row0 + w * 16 + lr) * K + k0 + lc * 8,
              &As[w * 512]);
#pragma unroll
      for (int i = 0; i < 2; i++) {
        int bi = w * 2 + i;
        gload16(WT + (size_t)(col0 + bi * 16 + lr) * K + k0 + lc * 8,
                &Bs[bi * 512]);
      }
    }
    __syncthreads();
    bf16x8 af[4], bf_[NT];
#pragma unroll
    for (int mt = 0; mt < 4; mt++) {
      int r = wm + mt * 16 + li;
      af[mt] = *(const bf16x8*)&As[r * 32 + ((g ^ (r & 3)) * 8)];
    }
#pragma unroll
    for (int nt = 0; nt < NT; nt++) {
      int r = wnb + nt * 16 + li;
      bf_[nt] = *(const bf16x8*)&Bs[r * 32 + ((g ^ (r & 3)) * 8)];
    }
#pragma unroll
    for (int mt = 0; mt < 4; mt++)
#pragma unroll
      for (int nt = 0; nt < NT; nt++)
        acc[mt][nt] = __builtin_amdgcn_mfma_f32_16x16x32_bf16(
            af[mt], bf_[nt], acc[mt][nt], 0, 0, 0);
    __syncthreads();
  }
#pragma unroll
  for (int mt = 0; mt < 4; mt++) {
#pragma unroll
    for (int nt = 0; nt < NT; nt++) {
#pragma unroll
      for (int r = 0; r < 4; r++) {
        int row = row0 + wm + mt * 16 + g * 4 + r;
        int col = col0 + wnb + nt * 16 + li;
        float v = acc[mt][nt][r];
        if (BIAS) v += bias[col];
        if (RES) v += res[(size_t)row * ldres + col];
        if (GELU_) v = 0.5f * v * (1.0f + erff(v * 0.70710678118654752f));
        if (OBF16)
          ((unsigned short*)Cv)[(size_t)row * ldc + col] = f2b(v);
        else
          ((float*)Cv)[(size_t)row * ldc + col] = v;
      }
    }
  }
}

// ---------------- transpose v slice of qkv -> vT [bh*64+d][L] ----------
__global__ __launch_bounds__(256) void vtrans_kernel(
    const unsigned short* __restrict__ qkv, unsigned short* __restrict__ vT) {
  __shared__ unsigned short t[64][65];
  int bh = blockIdx.y;
  int b = bh >> 3, h = bh & 7;
  int l0 = blockIdx.x * 64;
  int tid = threadIdx.x;
  int c = tid & 63, p = tid >> 6;
#pragma unroll
  for (int r = p; r < 64; r += 4)
    t[r][c] = qkv[(size_t)(b * LL + l0 + r) * 1536 + 1024 + h * 64 + c];
  __syncthreads();
#pragma unroll
  for (int r = p; r < 64; r += 4)
    vT[((size_t)bh * 64 + r) * LL + l0 + c] = t[c][r];
}

// ---------------- meanV over L per (b,h,d), from vT ----------------
__global__ __launch_bounds__(256) void meanv_kernel(
    const unsigned short* __restrict__ vT, float* __restrict__ meanV) {
  __shared__ float red[256];
  int bh = blockIdx.x;
  int tid = threadIdx.x;
  int d = tid >> 2, p = tid & 3;
  const unsigned short* vp = vT + ((size_t)bh * 64 + d) * LL;
  float s = 0.f;
  for (int i = p * 512; i < p * 512 + 512; i++) s += b2f(vp[i]);
  red[tid] = s;
  __syncthreads();
  if (p == 0)
    meanV[bh * 64 + d] =
        (red[tid] + red[tid + 1] + red[tid + 2] + red[tid + 3]) *
        (1.0f / (float)LL);
}

// ---------------- MFMA flash attention (v4: barrier-free) ----------------
// Grid 1024 = 32 bh x 32 qtiles, LPT + XCD-chunked remap. 4 waves, each wave
// owns 16 q-rows and runs FULLY INDEPENDENTLY: K and V B-frags read direct
// from global (L2-resident; each b128 instr = 16 full 64B lines), P repack
// through wave-private LDS. Zero __syncthreads -> waves self-pace, compiler
// pipelines loads across iterations, 4 blocks/CU.
__global__ __launch_bounds__(256, 4) void attn_kernel(
    const unsigned short* __restrict__ qkv, const unsigned short* __restrict__ vT,
    const int* __restrict__ etype, const float* __restrict__ meanV,
    unsigned short* __restrict__ ao) {
  __shared__ unsigned short Ps[4][16][132];  // wave-private P repack
  int hwbid = blockIdx.x;
  int work = (hwbid & 7) * 128 + (hwbid >> 3);
  int bh = work >> 5;
  int qt = 31 - (work & 31);  // LPT: big blocks first
  int h = bh & 7, b = bh >> 3;
  int q0 = qt * 64;
  int tid = threadIdx.x, w = tid >> 6, l = tid & 63;
  int g = l >> 4, li = l & 15;

  const unsigned short* qrp =
      qkv + (size_t)(b * LL + q0 + w * 16 + li) * 1536 + h * 64;
  bf16x8 aq0 = *(const bf16x8*)&qrp[g * 8];
  bf16x8 aq1 = *(const bf16x8*)&qrp[32 + g * 8];

  // per-lane K row base (row k0 + n*16 + li), d-cols h*64..
  const unsigned short* kbase =
      qkv + (size_t)(b * LL + li) * 1536 + 512 + h * 64;
  const unsigned short* vbase = vT + ((size_t)(bh * 64 + li)) * LL;
  const int* ebase = etype + b * LL + li;

  f32x4 o[4];
#pragma unroll
  for (int n = 0; n < 4; n++) o[n] = (f32x4){0.f, 0.f, 0.f, 0.f};
  float mreg[4], lreg[4];
#pragma unroll
  for (int r = 0; r < 4; r++) { mreg[r] = -3.0e38f; lreg[r] = 0.f; }

  int nt = (qt + 2) >> 1;  // 128-key tiles
  for (int j = 0; j < nt; j++) {
    int k0 = j << 7;
    // pad mask
    int kp8[8];
#pragma unroll
    for (int n = 0; n < 8; n++) kp8[n] = ebase[k0 + n * 16];
    // S = Q K^T, K direct from global
    f32x4 s[8];
#pragma unroll
    for (int n = 0; n < 8; n++) {
      const unsigned short* kb = kbase + (size_t)(k0 + n * 16) * 1536;
      bf16x8 bk0 = *(const bf16x8*)&kb[g * 8];
      bf16x8 bk1 = *(const bf16x8*)&kb[32 + g * 8];
      f32x4 a = (f32x4){0.f, 0.f, 0.f, 0.f};
      __builtin_amdgcn_s_setprio(1);
      a = __builtin_amdgcn_mfma_f32_16x16x32_bf16(aq0, bk0, a, 0, 0, 0);
      a = __builtin_amdgcn_mfma_f32_16x16x32_bf16(aq1, bk1, a, 0, 0, 0);
      __builtin_amdgcn_s_setprio(0);
      s[n] = a;
    }
    // V frags for k-slots 0,1 issued early (latency hidden under softmax)
    bf16x8 bva[4], bvb[4];
#pragma unroll
    for (int n = 0; n < 4; n++) {
      const unsigned short* vp = vbase + (size_t)(n * 16) * LL + k0;
      bva[n] = *(const bf16x8*)&vp[g * 8];
      bvb[n] = *(const bf16x8*)&vp[32 + g * 8];
    }
    // scale + mask
#pragma unroll
    for (int n = 0; n < 8; n++) {
      int key = k0 + n * 16 + li;
      bool pad = (kp8[n] == 0);
#pragma unroll
      for (int r = 0; r < 4; r++) {
        int qrow = q0 + w * 16 + g * 4 + r;
        float sv = s[n][r] * 0.125f;
        if (key > qrow || pad) sv = -1.0e9f;
        s[n][r] = sv;
      }
    }
    // wave-parallel online softmax (reduce across the 16 li lanes)
    float pm[4], corr[4], psum[4];
#pragma unroll
    for (int r = 0; r < 4; r++) {
      float m0 = fmaxf(fmaxf(s[0][r], s[1][r]), fmaxf(s[2][r], s[3][r]));
      float m1 = fmaxf(fmaxf(s[4][r], s[5][r]), fmaxf(s[6][r], s[7][r]));
      pm[r] = fmaxf(m0, m1);
    }
#pragma unroll
    for (int msk = 1; msk <= 8; msk <<= 1)
#pragma unroll
      for (int r = 0; r < 4; r++)
        pm[r] = fmaxf(pm[r], __shfl_xor(pm[r], msk, 64));
#pragma unroll
    for (int r = 0; r < 4; r++) {
      float mnew = fmaxf(mreg[r], pm[r]);
      corr[r] = __expf(mreg[r] - mnew);
      mreg[r] = mnew;
      float ps = 0.f;
#pragma unroll
      for (int n = 0; n < 8; n++) {
        float p = __expf(s[n][r] - mnew);
        s[n][r] = p;
        ps += p;
      }
      psum[r] = ps;
    }
#pragma unroll
    for (int msk = 1; msk <= 8; msk <<= 1)
#pragma unroll
      for (int r = 0; r < 4; r++) psum[r] += __shfl_xor(psum[r], msk, 64);
#pragma unroll
    for (int r = 0; r < 4; r++) lreg[r] = lreg[r] * corr[r] + psum[r];
    // P -> wave-private LDS (same-wave ds ordering via lgkmcnt, no barrier)
#pragma unroll
    for (int n = 0; n < 8; n++)
#pragma unroll
      for (int r = 0; r < 4; r++)
        Ps[w][g * 4 + r][n * 16 + li] = f2b(s[n][r]);
    // rescale O
#pragma unroll
    for (int n = 0; n < 4; n++)
#pragma unroll
      for (int r = 0; r < 4; r++) o[n][r] *= corr[r];
    // PV k-slot 0 + issue loads for slots 2,3
    bf16x8 ap0 = *(const bf16x8*)&Ps[w][li][g * 8];
    bf16x8 bvc[4], bvd[4];
#pragma unroll
    for (int n = 0; n < 4; n++) {
      const unsigned short* vp = vbase + (size_t)(n * 16) * LL + k0 + 64;
      bvc[n] = *(const bf16x8*)&vp[g * 8];
      bvd[n] = *(const bf16x8*)&vp[32 + g * 8];
    }
    __builtin_amdgcn_s_setprio(1);
#pragma unroll
    for (int n = 0; n < 4; n++)
      o[n] = __builtin_amdgcn_mfma_f32_16x16x32_bf16(ap0, bva[n], o[n], 0, 0, 0);
    __builtin_amdgcn_s_setprio(0);
    bf16x8 ap1 = *(const bf16x8*)&Ps[w][li][32 + g * 8];
    bf16x8 ap2 = *(const bf16x8*)&Ps[w][li][64 + g * 8];
    bf16x8 ap3 = *(const bf16x8*)&Ps[w][li][96 + g * 8];
    __builtin_amdgcn_s_setprio(1);
#pragma unroll
    for (int n = 0; n < 4; n++)
      o[n] = __builtin_amdgcn_mfma_f32_16x16x32_bf16(ap1, bvb[n], o[n], 0, 0, 0);
#pragma unroll
    for (int n = 0; n < 4; n++)
      o[n] = __builtin_amdgcn_mfma_f32_16x16x32_bf16(ap2, bvc[n], o[n], 0, 0, 0);
#pragma unroll
    for (int n = 0; n < 4; n++)
      o[n] = __builtin_amdgcn_mfma_f32_16x16x32_bf16(ap3, bvd[n], o[n], 0, 0, 0);
    __builtin_amdgcn_s_setprio(0);
  }
  // epilogue
#pragma unroll
  for (int r = 0; r < 4; r++) {
    int qr = q0 + w * 16 + g * 4 + r;
    float inv = 1.0f / lreg[r];
    bool dead = (mreg[r] <= -1.0e8f);
#pragma unroll
    for (int n = 0; n < 4; n++) {
      float v = dead ? meanV[bh * 64 + n * 16 + li] : o[n][r] * inv;
      ao[(size_t)(b * LL + qr) * DD + h * 64 + n * 16 + li] = f2b(v);
    }
  }
}

// ---------------- LayerNorm (+npm) -> fp32 + bf16 ----------------
__global__ __launch_bounds__(256) void ln_kernel(
    const float* __restrict__ in, const float* __restrict__ g,
    const float* __restrict__ bta, const float* __restrict__ npm,
    float* __restrict__ out, unsigned short* __restrict__ out_bf) {
  __shared__ float red[4];
  int row = blockIdx.x;
  int tid = threadIdx.x;
  const float* rp = in + (size_t)row * DD;
  float v0 = rp[tid], v1 = rp[tid + 256];
  float s = v0 + v1;
#pragma unroll
  for (int o = 32; o > 0; o >>= 1) s += __shfl_down(s, o, 64);
  if ((tid & 63) == 0) red[tid >> 6] = s;
  __syncthreads();
  float mean = (red[0] + red[1] + red[2] + red[3]) * (1.0f / (float)DD);
  float d0 = v0 - mean, d1 = v1 - mean;
  float sq = d0 * d0 + d1 * d1;
#pragma unroll
  for (int o = 32; o > 0; o >>= 1) sq += __shfl_down(sq, o, 64);
  __syncthreads();
  if ((tid & 63) == 0) red[tid >> 6] = sq;
  __syncthreads();
  float var = (red[0] + red[1] + red[2] + red[3]) * (1.0f / (float)DD);
  float rstd = rsqrtf(var + 1e-6f);
  float m = npm[row];
  float o0 = (d0 * rstd * g[tid] + bta[tid]) * m;
  float o1 = (d1 * rstd * g[tid + 256] + bta[tid + 256]) * m;
  out[(size_t)row * DD + tid] = o0;
  out[(size_t)row * DD + tid + 256] = o1;
  out_bf[(size_t)row * DD + tid] = f2b(o0);
  out_bf[(size_t)row * DD + tid + 256] = f2b(o1);
}

extern "C" void kernel_launch(void* const* d_in, const int* in_sizes, int n_in,
                              void* d_out, int out_size, void* d_ws,
                              size_t ws_size, hipStream_t stream) {
  const int* etype = (const int*)d_in[0];
  const float* etime = (const float*)d_in[1];
  const float* npm = (const float*)d_in[2];
  const float* emb = (const float*)d_in[3];
  const float* Wq = (const float*)d_in[4];
  const float* Wk = (const float*)d_in[5];
  const float* Wv = (const float*)d_in[6];
  const float* fc_w = (const float*)d_in[7];
  const float* fc_b = (const float*)d_in[8];
  const float* ln1_g = (const float*)d_in[9];
  const float* ln1_b = (const float*)d_in[10];
  const float* W1 = (const float*)d_in[11];
  const float* b1 = (const float*)d_in[12];
  const float* W2 = (const float*)d_in[13];
  const float* b2 = (const float*)d_in[14];
  const float* ln2_g = (const float*)d_in[15];
  const float* ln2_b = (const float*)d_in[16];

  float* x = (float*)d_out;
  char* ws = (char*)d_ws;
  const size_t SZF = (size_t)MM * DD * sizeof(float);
  const size_t SZB = (size_t)MM * DD * sizeof(short);
  float* tem = (float*)ws; ws += SZF;
  float* xa  = (float*)ws; ws += SZF;
  unsigned short* xab = (unsigned short*)ws; ws += SZB;
  unsigned short* xbf = (unsigned short*)ws; ws += SZB;
  unsigned short* qkv = (unsigned short*)ws; ws += (size_t)MM * 1536 * 2;
  unsigned short* vT  = (unsigned short*)ws; ws += (size_t)BB * NH * 64 * LL * 2;
  unsigned short* ao  = (unsigned short*)ws; ws += SZB;
  unsigned short* hb  = (unsigned short*)ws; ws += (size_t)MM * DINNER * 2;
  float* yb = (float*)ws; ws += SZF;
  unsigned short* qkvT = (unsigned short*)ws; ws += (size_t)NLAYERS * 1536 * 512 * 2;
  unsigned short* fcT  = (unsigned short*)ws; ws += (size_t)NLAYERS * 512 * 512 * 2;
  unsigned short* W1T  = (unsigned short*)ws; ws += (size_t)NLAYERS * 2048 * 512 * 2;
  unsigned short* W2T  = (unsigned short*)ws; ws += (size_t)NLAYERS * 512 * 2048 * 2;
  float* meanV = (float*)ws; ws += BB * NH * 64 * sizeof(float);

  init_kernel<<<MM, 512, 0, stream>>>(etype, etime, npm, emb, tem, x);

  wtrans_kernel<<<dim3(16, 16, NLAYERS), 256, 0, stream>>>(
      Wq, qkvT + 0 * 512 * 512, 512, 512, 512L * 512, 1536L * 512);
  wtrans_kernel<<<dim3(16, 16, NLAYERS), 256, 0, stream>>>(
      Wk, qkvT + 1 * 512 * 512, 512, 512, 512L * 512, 1536L * 512);
  wtrans_kernel<<<dim3(16, 16, NLAYERS), 256, 0, stream>>>(
      Wv, qkvT + 2 * 512 * 512, 512, 512, 512L * 512, 1536L * 512);
  wtrans_kernel<<<dim3(16, 16, NLAYERS), 256, 0, stream>>>(
      fc_w, fcT, 512, 512, 512L * 512, 512L * 512);
  wtrans_kernel<<<dim3(64, 16, NLAYERS), 256, 0, stream>>>(
      W1, W1T, 512, 2048, 512L * 2048, 2048L * 512);
  wtrans_kernel<<<dim3(16, 64, NLAYERS), 256, 0, stream>>>(
      W2, W2T, 2048, 512, 2048L * 512, 512L * 2048);

  for (int l = 0; l < NLAYERS; l++) {
    add_tem_kernel<<<(MM * DD / 4) / 256, 256, 0, stream>>>(
        (const float4*)x, (const float4*)tem, (float4*)xa, (us4*)xab);

    gemm_kernel<128, false, false, false, true><<<dim3(12, 64), 256, 0, stream>>>(
        xab, qkvT + (size_t)l * 1536 * 512, nullptr, nullptr, 0, qkv, 1536,
        MM, 1536, 512);

    vtrans_kernel<<<dim3(32, 32), 256, 0, stream>>>(qkv, vT);
    meanv_kernel<<<BB * NH, 256, 0, stream>>>(vT, meanV);
    attn_kernel<<<BB * NH * 32, 256, 0, stream>>>(qkv, vT, etype, meanV, ao);

    gemm_kernel<64, true, true, false, false><<<dim3(4, 128), 256, 0, stream>>>(
        ao, fcT + (size_t)l * 512 * 512, fc_b + (size_t)l * 512, xa, 512, yb,
        512, MM, 512, 512);
    ln_kernel<<<MM, 256, 0, stream>>>(yb, ln1_g + (size_t)l * 512,
                                      ln1_b + (size_t)l * 512, npm, x, xbf);

    gemm_kernel<128, true, false, true, true><<<dim3(16, 64), 256, 0, stream>>>(
        xbf, W1T + (size_t)l * 2048 * 512, b1 + (size_t)l * 2048, nullptr, 0,
        hb, 2048, MM, 2048, 512);
    gemm_kernel<64, true, true, false, false><<<dim3(4, 128), 256, 0, stream>>>(
        hb, W2T + (size_t)l * 512 * 2048, b2 + (size_t)l * 512, x, 512, yb,
        512, MM, 512, 2048);
    ln_kernel<<<MM, 256, 0, stream>>>(yb, ln2_g + (size_t)l * 512,
                                      ln2_b + (size_t)l * 512, npm, x, xbf);
  }
}

// Round 6
// 1130.440 us; speedup vs baseline: 1.4738x; 1.4738x over previous
//
#include <hip/hip_runtime.h>
#include <math.h>

#define BB 4
#define LL 2048
#define DD 512
#define NH 8
#define DINNER 2048
#define NLAYERS 4
#define MM (BB * LL)  // 8192

typedef __attribute__((ext_vector_type(8))) __bf16 bf16x8;
typedef __attribute__((ext_vector_type(4))) float f32x4;
typedef __attribute__((ext_vector_type(4))) unsigned short us4;

__device__ __forceinline__ unsigned short f2b(float f) {
  union { float f; unsigned u; } v; v.f = f;
  unsigned r = v.u + 0x7fffu + ((v.u >> 16) & 1u);
  return (unsigned short)(r >> 16);
}
__device__ __forceinline__ float b2f(unsigned short h) {
  union { unsigned u; float f; } v; v.u = ((unsigned)h) << 16; return v.f;
}

__device__ __forceinline__ void gload16(const void* g, void* l) {
  __builtin_amdgcn_global_load_lds(
      (const __attribute__((address_space(1))) void*)g,
      (__attribute__((address_space(3))) void*)l, 16, 0, 0);
}

// ---------------- init: temporal enc + embedding gather ----------------
__global__ __launch_bounds__(512) void init_kernel(
    const int* __restrict__ etype, const float* __restrict__ etime,
    const float* __restrict__ npm, const float* __restrict__ emb,
    float* __restrict__ tem, float* __restrict__ x) {
  int row = blockIdx.x;
  int d = threadIdx.x;
  float t = etime[row];
  float mask = npm[row];
  int dd = d & ~1;
  float pv = expf(9.210340371976184f * ((float)dd * (1.0f / (float)DD)));
  float r = t / pv;
  float val = (d & 1) ? cosf(r) : sinf(r);
  tem[(size_t)row * DD + d] = val * mask;
  int ty = etype[row];
  x[(size_t)row * DD + d] = emb[(size_t)ty * DD + d];
}

// ---------------- x + tem -> fp32 + bf16 ----------------
__global__ __launch_bounds__(256) void add_tem_kernel(
    const float4* __restrict__ x, const float4* __restrict__ tem,
    float4* __restrict__ xa, us4* __restrict__ xab) {
  int i = blockIdx.x * 256 + threadIdx.x;
  float4 a = x[i], t = tem[i];
  float4 s = make_float4(a.x + t.x, a.y + t.y, a.z + t.z, a.w + t.w);
  xa[i] = s;
  us4 p = {f2b(s.x), f2b(s.y), f2b(s.z), f2b(s.w)};
  xab[i] = p;
}

// ---------------- weight transpose+convert: fp32 [K][N] -> bf16 [N][K] ----
__global__ __launch_bounds__(256) void wtrans_kernel(
    const float* __restrict__ in, unsigned short* __restrict__ out,
    int K, int N, long in_ls, long out_ls) {
  __shared__ float t[32][33];
  int l = blockIdx.z;
  int n0 = blockIdx.x * 32, k0 = blockIdx.y * 32;
  int tx = threadIdx.x & 31, ty = threadIdx.x >> 5;
  const float* ip = in + (size_t)l * in_ls;
  unsigned short* op = out + (size_t)l * out_ls;
#pragma unroll
  for (int r = ty; r < 32; r += 8)
    t[r][tx] = ip[(size_t)(k0 + r) * N + n0 + tx];
  __syncthreads();
#pragma unroll
  for (int r = ty; r < 32; r += 8)
    op[(size_t)(n0 + r) * K + k0 + tx] = f2b(t[tx][r]);
}

// ---- MFMA GEMM, 2-phase pipelined (T3-min): C = A(bf16 [M,K]) @ WT^T ----
// Per k-step: STAGE(next tile -> other buf) || ds_read+MFMA(cur buf),
// ONE barrier (drains own vmcnt + lgkm). LDS double-buffered.
template <int BM, bool BIAS, bool RES, bool GELU_, bool OBF16>
__global__ __launch_bounds__(256) void gemm_kernel(
    const unsigned short* __restrict__ A, const unsigned short* __restrict__ WT,
    const float* __restrict__ bias, const float* __restrict__ res, int ldres,
    void* __restrict__ Cv, int ldc, int M, int N, int K) {
  __shared__ unsigned short As[2][BM * 32];
  __shared__ unsigned short Bs[2][128 * 32];
  constexpr int NT = (BM == 128) ? 4 : 2;  // per-wave 16-col tiles
  int tid = threadIdx.x;
  int w = tid >> 6, l = tid & 63;
  int li = l & 15, g = l >> 4;
  int row0 = blockIdx.y * BM, col0 = blockIdx.x * 128;
  int wm = (BM == 128) ? (w & 1) * 64 : 0;         // row base within tile
  int wnb = (BM == 128) ? (w >> 1) * 64 : w * 32;  // col base within tile
  f32x4 acc[4][NT];
#pragma unroll
  for (int i = 0; i < 4; i++)
#pragma unroll
    for (int j = 0; j < NT; j++) acc[i][j] = (f32x4){0.f, 0.f, 0.f, 0.f};

  int lr = l >> 2;
  int lc = (l & 3) ^ (lr & 3);

  auto stage = [&](int bb, int kb) {
    int k0 = kb * 32;
    if (BM == 128) {
#pragma unroll
      for (int i = 0; i < 2; i++) {
        int ai = w * 2 + i;
        gload16(A + (size_t)(row0 + ai * 16 + lr) * K + k0 + lc * 8,
                &As[bb][ai * 512]);
        gload16(WT + (size_t)(col0 + ai * 16 + lr) * K + k0 + lc * 8,
                &Bs[bb][ai * 512]);
      }
    } else {
      gload16(A + (size_t)(row0 + w * 16 + lr) * K + k0 + lc * 8,
              &As[bb][w * 512]);
#pragma unroll
      for (int i = 0; i < 2; i++) {
        int bi = w * 2 + i;
        gload16(WT + (size_t)(col0 + bi * 16 + lr) * K + k0 + lc * 8,
                &Bs[bb][bi * 512]);
      }
    }
  };

  int nk = K >> 5;
  stage(0, 0);
  __syncthreads();  // prologue tile ready (implicit vmcnt(0))
  int buf = 0;
  for (int kb = 0; kb < nk; kb++) {
    if (kb + 1 < nk) stage(buf ^ 1, kb + 1);  // overlaps compute below
    bf16x8 af[4], bf_[NT];
#pragma unroll
    for (int mt = 0; mt < 4; mt++) {
      int r = wm + mt * 16 + li;
      af[mt] = *(const bf16x8*)&As[buf][r * 32 + ((g ^ (r & 3)) * 8)];
    }
#pragma unroll
    for (int nt = 0; nt < NT; nt++) {
      int r = wnb + nt * 16 + li;
      bf_[nt] = *(const bf16x8*)&Bs[buf][r * 32 + ((g ^ (r & 3)) * 8)];
    }
#pragma unroll
    for (int mt = 0; mt < 4; mt++)
#pragma unroll
      for (int nt = 0; nt < NT; nt++)
        acc[mt][nt] = __builtin_amdgcn_mfma_f32_16x16x32_bf16(
            af[mt], bf_[nt], acc[mt][nt], 0, 0, 0);
    __syncthreads();  // next tile staged + everyone done reading buf
    buf ^= 1;
  }
#pragma unroll
  for (int mt = 0; mt < 4; mt++) {
#pragma unroll
    for (int nt = 0; nt < NT; nt++) {
#pragma unroll
      for (int r = 0; r < 4; r++) {
        int row = row0 + wm + mt * 16 + g * 4 + r;
        int col = col0 + wnb + nt * 16 + li;
        float v = acc[mt][nt][r];
        if (BIAS) v += bias[col];
        if (RES) v += res[(size_t)row * ldres + col];
        if (GELU_) v = 0.5f * v * (1.0f + erff(v * 0.70710678118654752f));
        if (OBF16)
          ((unsigned short*)Cv)[(size_t)row * ldc + col] = f2b(v);
        else
          ((float*)Cv)[(size_t)row * ldc + col] = v;
      }
    }
  }
}

// ---------------- transpose v slice of qkv -> vT [bh*64+d][L] ----------
__global__ __launch_bounds__(256) void vtrans_kernel(
    const unsigned short* __restrict__ qkv, unsigned short* __restrict__ vT) {
  __shared__ unsigned short t[64][65];
  int bh = blockIdx.y;
  int b = bh >> 3, h = bh & 7;
  int l0 = blockIdx.x * 64;
  int tid = threadIdx.x;
  int c = tid & 63, p = tid >> 6;
#pragma unroll
  for (int r = p; r < 64; r += 4)
    t[r][c] = qkv[(size_t)(b * LL + l0 + r) * 1536 + 1024 + h * 64 + c];
  __syncthreads();
#pragma unroll
  for (int r = p; r < 64; r += 4)
    vT[((size_t)bh * 64 + r) * LL + l0 + c] = t[c][r];
}

// ---------------- meanV over L per (b,h,d), from vT ----------------
__global__ __launch_bounds__(256) void meanv_kernel(
    const unsigned short* __restrict__ vT, float* __restrict__ meanV) {
  __shared__ float red[256];
  int bh = blockIdx.x;
  int tid = threadIdx.x;
  int d = tid >> 2, p = tid & 3;
  const unsigned short* vp = vT + ((size_t)bh * 64 + d) * LL;
  float s = 0.f;
  for (int i = p * 512; i < p * 512 + 512; i++) s += b2f(vp[i]);
  red[tid] = s;
  __syncthreads();
  if (p == 0)
    meanV[bh * 64 + d] =
        (red[tid] + red[tid + 1] + red[tid + 2] + red[tid + 3]) *
        (1.0f / (float)LL);
}

// ---------------- MFMA flash attention (round-4 structure, KVBLK=128) ----
// Grid 1024 = 32 bh x 32 qtiles, LPT + XCD-chunked remap. 4 waves, each wave
// owns 16 q-rows. Per iteration: 128 keys, ONE barrier, ONE softmax pass.
__global__ __launch_bounds__(256) void attn_kernel(
    const unsigned short* __restrict__ qkv, const unsigned short* __restrict__ vT,
    const int* __restrict__ etype, const float* __restrict__ meanV,
    unsigned short* __restrict__ ao) {
  __shared__ unsigned short Ks[2][128 * 64];  // [buf][key*64+d], swizzled 16KB
  __shared__ unsigned short Ps[64][136];      // [qrow][key 0..127]
  int hwbid = blockIdx.x;
  int work = (hwbid & 7) * 128 + (hwbid >> 3);
  int bh = work >> 5;
  int qt = 31 - (work & 31);  // LPT: big blocks first
  int h = bh & 7, b = bh >> 3;
  int q0 = qt * 64;
  int tid = threadIdx.x, w = tid >> 6, l = tid & 63;
  int g = l >> 4, li = l & 15;

  const unsigned short* qrp =
      qkv + (size_t)(b * LL + q0 + w * 16 + li) * 1536 + h * 64;
  bf16x8 aq0 = *(const bf16x8*)&qrp[g * 8];
  bf16x8 aq1 = *(const bf16x8*)&qrp[32 + g * 8];

  f32x4 o[4];
#pragma unroll
  for (int n = 0; n < 4; n++) o[n] = (f32x4){0.f, 0.f, 0.f, 0.f};
  float mreg[4], lreg[4];
#pragma unroll
  for (int r = 0; r < 4; r++) { mreg[r] = -3.0e38f; lreg[r] = 0.f; }

  int nt = (qt + 2) >> 1;  // 128-key tiles (last may be half-masked)
  // prologue: stage tile 0 into buf 0 (128 rows x 128B, 4 issues/thread)
#pragma unroll
  for (int e = 0; e < 4; e++) {
    int idx = e * 256 + tid;
    int r = idx >> 3;
    int src = (l & 7) ^ (r & 7);
    gload16(qkv + (size_t)(b * LL + r) * 1536 + 512 + h * 64 + src * 8,
            &Ks[0][(e * 256 + w * 64) * 8]);
  }
  __syncthreads();

  int cur = 0;
  for (int j = 0; j < nt; j++) {
    int k0 = j << 7;
    if (j + 1 < nt) {
#pragma unroll
      for (int e = 0; e < 4; e++) {
        int idx = e * 256 + tid;
        int r = idx >> 3;
        int src = (l & 7) ^ (r & 7);
        gload16(qkv + (size_t)(b * LL + k0 + 128 + r) * 1536 + 512 + h * 64 +
                    src * 8,
                &Ks[cur ^ 1][(e * 256 + w * 64) * 8]);
      }
    }
    // pad mask for this tile (8 subtiles)
    int kp8[8];
#pragma unroll
    for (int n = 0; n < 8; n++) kp8[n] = etype[b * LL + k0 + n * 16 + li];
    // S = Q K^T over 128 keys
    f32x4 s[8];
#pragma unroll
    for (int n = 0; n < 8; n++) {
      int rK = n * 16 + li;
      const unsigned short* kb = &Ks[cur][rK * 64];
      bf16x8 bk0 = *(const bf16x8*)&kb[(g ^ (rK & 7)) * 8];
      bf16x8 bk1 = *(const bf16x8*)&kb[((g + 4) ^ (rK & 7)) * 8];
      f32x4 a = (f32x4){0.f, 0.f, 0.f, 0.f};
      __builtin_amdgcn_s_setprio(1);
      a = __builtin_amdgcn_mfma_f32_16x16x32_bf16(aq0, bk0, a, 0, 0, 0);
      a = __builtin_amdgcn_mfma_f32_16x16x32_bf16(aq1, bk1, a, 0, 0, 0);
      __builtin_amdgcn_s_setprio(0);
      s[n] = a;
    }
    // scale + mask
#pragma unroll
    for (int n = 0; n < 8; n++) {
      int key = k0 + n * 16 + li;
      bool pad = (kp8[n] == 0);
#pragma unroll
      for (int r = 0; r < 4; r++) {
        int qrow = q0 + w * 16 + g * 4 + r;
        float sv = s[n][r] * 0.125f;
        if (key > qrow || pad) sv = -1.0e9f;
        s[n][r] = sv;
      }
    }
    // wave-parallel online softmax (reduce across 16 li lanes)
    float pm[4], corr[4], psum[4];
#pragma unroll
    for (int r = 0; r < 4; r++) {
      float m0 = fmaxf(fmaxf(s[0][r], s[1][r]), fmaxf(s[2][r], s[3][r]));
      float m1 = fmaxf(fmaxf(s[4][r], s[5][r]), fmaxf(s[6][r], s[7][r]));
      pm[r] = fmaxf(m0, m1);
    }
#pragma unroll
    for (int msk = 1; msk <= 8; msk <<= 1)
#pragma unroll
      for (int r = 0; r < 4; r++)
        pm[r] = fmaxf(pm[r], __shfl_xor(pm[r], msk, 64));
#pragma unroll
    for (int r = 0; r < 4; r++) {
      float mnew = fmaxf(mreg[r], pm[r]);
      corr[r] = __expf(mreg[r] - mnew);
      mreg[r] = mnew;
      float ps = 0.f;
#pragma unroll
      for (int n = 0; n < 8; n++) {
        float p = __expf(s[n][r] - mnew);
        s[n][r] = p;
        ps += p;
      }
      psum[r] = ps;
    }
#pragma unroll
    for (int msk = 1; msk <= 8; msk <<= 1)
#pragma unroll
      for (int r = 0; r < 4; r++) psum[r] += __shfl_xor(psum[r], msk, 64);
#pragma unroll
    for (int r = 0; r < 4; r++) lreg[r] = lreg[r] * corr[r] + psum[r];
    // P -> LDS (own-wave rows only)
#pragma unroll
    for (int n = 0; n < 8; n++)
#pragma unroll
      for (int r = 0; r < 4; r++)
        Ps[w * 16 + g * 4 + r][n * 16 + li] = f2b(s[n][r]);
    // rescale O
#pragma unroll
    for (int n = 0; n < 4; n++)
#pragma unroll
      for (int r = 0; r < 4; r++) o[n][r] *= corr[r];
    // PV over 4 k-slots of 32 keys; V frags loaded per-slot (short liveness)
#pragma unroll
    for (int ks = 0; ks < 4; ks++) {
      bf16x8 ap = *(const bf16x8*)&Ps[w * 16 + li][ks * 32 + g * 8];
      bf16x8 bv[4];
#pragma unroll
      for (int n = 0; n < 4; n++)
        bv[n] = *(const bf16x8*)&vT[((size_t)(bh * 64 + n * 16 + li)) * LL +
                                    k0 + ks * 32 + g * 8];
      __builtin_amdgcn_s_setprio(1);
#pragma unroll
      for (int n = 0; n < 4; n++)
        o[n] = __builtin_amdgcn_mfma_f32_16x16x32_bf16(ap, bv[n], o[n], 0, 0, 0);
      __builtin_amdgcn_s_setprio(0);
    }
    __syncthreads();  // drains prefetch (vmcnt) + Ks/Ps traffic
    cur ^= 1;
  }
  // epilogue
#pragma unroll
  for (int r = 0; r < 4; r++) {
    int qr = q0 + w * 16 + g * 4 + r;
    float inv = 1.0f / lreg[r];
    bool dead = (mreg[r] <= -1.0e8f);
#pragma unroll
    for (int n = 0; n < 4; n++) {
      float v = dead ? meanV[bh * 64 + n * 16 + li] : o[n][r] * inv;
      ao[(size_t)(b * LL + qr) * DD + h * 64 + n * 16 + li] = f2b(v);
    }
  }
}

// ---------------- LayerNorm (+npm) -> fp32 + bf16 ----------------
__global__ __launch_bounds__(256) void ln_kernel(
    const float* __restrict__ in, const float* __restrict__ g,
    const float* __restrict__ bta, const float* __restrict__ npm,
    float* __restrict__ out, unsigned short* __restrict__ out_bf) {
  __shared__ float red[4];
  int row = blockIdx.x;
  int tid = threadIdx.x;
  const float* rp = in + (size_t)row * DD;
  float v0 = rp[tid], v1 = rp[tid + 256];
  float s = v0 + v1;
#pragma unroll
  for (int o = 32; o > 0; o >>= 1) s += __shfl_down(s, o, 64);
  if ((tid & 63) == 0) red[tid >> 6] = s;
  __syncthreads();
  float mean = (red[0] + red[1] + red[2] + red[3]) * (1.0f / (float)DD);
  float d0 = v0 - mean, d1 = v1 - mean;
  float sq = d0 * d0 + d1 * d1;
#pragma unroll
  for (int o = 32; o > 0; o >>= 1) sq += __shfl_down(sq, o, 64);
  __syncthreads();
  if ((tid & 63) == 0) red[tid >> 6] = sq;
  __syncthreads();
  float var = (red[0] + red[1] + red[2] + red[3]) * (1.0f / (float)DD);
  float rstd = rsqrtf(var + 1e-6f);
  float m = npm[row];
  float o0 = (d0 * rstd * g[tid] + bta[tid]) * m;
  float o1 = (d1 * rstd * g[tid + 256] + bta[tid + 256]) * m;
  out[(size_t)row * DD + tid] = o0;
  out[(size_t)row * DD + tid + 256] = o1;
  out_bf[(size_t)row * DD + tid] = f2b(o0);
  out_bf[(size_t)row * DD + tid + 256] = f2b(o1);
}

extern "C" void kernel_launch(void* const* d_in, const int* in_sizes, int n_in,
                              void* d_out, int out_size, void* d_ws,
                              size_t ws_size, hipStream_t stream) {
  const int* etype = (const int*)d_in[0];
  const float* etime = (const float*)d_in[1];
  const float* npm = (const float*)d_in[2];
  const float* emb = (const float*)d_in[3];
  const float* Wq = (const float*)d_in[4];
  const float* Wk = (const float*)d_in[5];
  const float* Wv = (const float*)d_in[6];
  const float* fc_w = (const float*)d_in[7];
  const float* fc_b = (const float*)d_in[8];
  const float* ln1_g = (const float*)d_in[9];
  const float* ln1_b = (const float*)d_in[10];
  const float* W1 = (const float*)d_in[11];
  const float* b1 = (const float*)d_in[12];
  const float* W2 = (const float*)d_in[13];
  const float* b2 = (const float*)d_in[14];
  const float* ln2_g = (const float*)d_in[15];
  const float* ln2_b = (const float*)d_in[16];

  float* x = (float*)d_out;
  char* ws = (char*)d_ws;
  const size_t SZF = (size_t)MM * DD * sizeof(float);
  const size_t SZB = (size_t)MM * DD * sizeof(short);
  float* tem = (float*)ws; ws += SZF;
  float* xa  = (float*)ws; ws += SZF;
  unsigned short* xab = (unsigned short*)ws; ws += SZB;
  unsigned short* xbf = (unsigned short*)ws; ws += SZB;
  unsigned short* qkv = (unsigned short*)ws; ws += (size_t)MM * 1536 * 2;
  unsigned short* vT  = (unsigned short*)ws; ws += (size_t)BB * NH * 64 * LL * 2;
  unsigned short* ao  = (unsigned short*)ws; ws += SZB;
  unsigned short* hb  = (unsigned short*)ws; ws += (size_t)MM * DINNER * 2;
  float* yb = (float*)ws; ws += SZF;
  unsigned short* qkvT = (unsigned short*)ws; ws += (size_t)NLAYERS * 1536 * 512 * 2;
  unsigned short* fcT  = (unsigned short*)ws; ws += (size_t)NLAYERS * 512 * 512 * 2;
  unsigned short* W1T  = (unsigned short*)ws; ws += (size_t)NLAYERS * 2048 * 512 * 2;
  unsigned short* W2T  = (unsigned short*)ws; ws += (size_t)NLAYERS * 512 * 2048 * 2;
  float* meanV = (float*)ws; ws += BB * NH * 64 * sizeof(float);

  init_kernel<<<MM, 512, 0, stream>>>(etype, etime, npm, emb, tem, x);

  wtrans_kernel<<<dim3(16, 16, NLAYERS), 256, 0, stream>>>(
      Wq, qkvT + 0 * 512 * 512, 512, 512, 512L * 512, 1536L * 512);
  wtrans_kernel<<<dim3(16, 16, NLAYERS), 256, 0, stream>>>(
      Wk, qkvT + 1 * 512 * 512, 512, 512, 512L * 512, 1536L * 512);
  wtrans_kernel<<<dim3(16, 16, NLAYERS), 256, 0, stream>>>(
      Wv, qkvT + 2 * 512 * 512, 512, 512, 512L * 512, 1536L * 512);
  wtrans_kernel<<<dim3(16, 16, NLAYERS), 256, 0, stream>>>(
      fc_w, fcT, 512, 512, 512L * 512, 512L * 512);
  wtrans_kernel<<<dim3(64, 16, NLAYERS), 256, 0, stream>>>(
      W1, W1T, 512, 2048, 512L * 2048, 2048L * 512);
  wtrans_kernel<<<dim3(16, 64, NLAYERS), 256, 0, stream>>>(
      W2, W2T, 2048, 512, 2048L * 512, 512L * 2048);

  for (int l = 0; l < NLAYERS; l++) {
    add_tem_kernel<<<(MM * DD / 4) / 256, 256, 0, stream>>>(
        (const float4*)x, (const float4*)tem, (float4*)xa, (us4*)xab);

    gemm_kernel<128, false, false, false, true><<<dim3(12, 64), 256, 0, stream>>>(
        xab, qkvT + (size_t)l * 1536 * 512, nullptr, nullptr, 0, qkv, 1536,
        MM, 1536, 512);

    vtrans_kernel<<<dim3(32, 32), 256, 0, stream>>>(qkv, vT);
    meanv_kernel<<<BB * NH, 256, 0, stream>>>(vT, meanV);
    attn_kernel<<<BB * NH * 32, 256, 0, stream>>>(qkv, vT, etype, meanV, ao);

    gemm_kernel<64, true, true, false, false><<<dim3(4, 128), 256, 0, stream>>>(
        ao, fcT + (size_t)l * 512 * 512, fc_b + (size_t)l * 512, xa, 512, yb,
        512, MM, 512, 512);
    ln_kernel<<<MM, 256, 0, stream>>>(yb, ln1_g + (size_t)l * 512,
                                      ln1_b + (size_t)l * 512, npm, x, xbf);

    gemm_kernel<128, true, false, true, true><<<dim3(16, 64), 256, 0, stream>>>(
        xbf, W1T + (size_t)l * 2048 * 512, b1 + (size_t)l * 2048, nullptr, 0,
        hb, 2048, MM, 2048, 512);
    gemm_kernel<64, true, true, false, false><<<dim3(4, 128), 256, 0, stream>>>(
        hb, W2T + (size_t)l * 512 * 2048, b2 + (size_t)l * 512, x, 512, yb,
        512, MM, 512, 2048);
    ln_kernel<<<MM, 256, 0, stream>>>(yb, ln2_g + (size_t)l * 512,
                                      ln2_b + (size_t)l * 512, npm, x, xbf);
  }
}